// Round 1
// baseline (1046.838 us; speedup 1.0000x reference)
//
#include <hip/hip_runtime.h>
#include <cstdint>

// LinearGlobalAttention: out = ((elu(xWq^T)+1) @ M) * z + bo
//   M = (k^T v) @ Wo^T,  k = elu(xWk^T)+1, v = xWv^T, z = 1/max(q@ksum,1e-6)
// N=262144, C=256. Two fused passes over x + tiny mid kernels.
// MFMA 16x16x32 bf16; verified layouts: A[m=lane&15][k=(lane>>4)*8+j],
// C/D: col=lane&15, row=(lane>>4)*4+reg.
//
// R1 changes: 1024-thread blocks (16 waves, <=128 regs/wave -> 4 waves/SIMD,
// 2x occupancy); wave owns 16 kv cols (kvacc 64 regs); exclusive fp32 kv
// partial slots sized to ws (E store + S=4 shared atomic slots) to kill the
// 16.7M-global-atomic path; lane-contiguous coalesced staging; phase2
// next-tile register prefetch.

typedef __attribute__((ext_vector_type(8))) short short8;
typedef __attribute__((ext_vector_type(4))) float f32x4;
typedef unsigned short u16;
typedef unsigned int u32;

#define MFMA16(a, b, c) __builtin_amdgcn_mfma_f32_16x16x32_bf16(a, b, c, 0, 0, 0)

__device__ __forceinline__ u32 bf16_1(float f) {
  u32 u = __float_as_uint(f);
  return (u + 0x7FFFu + ((u >> 16) & 1u)) >> 16;  // RNE
}
__device__ __forceinline__ u32 bf16pk(float lo, float hi) {
  return bf16_1(lo) | (bf16_1(hi) << 16);
}

// ---------------------------------------------------------------- prep ------
// Zero ksum + the S shared kv-partial slots; build pre-swizzled bf16 B-operand
// fragments for Wq/Wk/Wv: element (c,d) of W (y = x W^T, so B[k=d][n=c]=W[c][d]).
__global__ void prep_kernel(const float* __restrict__ Wq, const float* __restrict__ Wk,
                            const float* __restrict__ Wv, u16* __restrict__ WqF,
                            u16* __restrict__ WkF, u16* __restrict__ WvF,
                            float* __restrict__ kvp, float* __restrict__ ksum,
                            int E, int S) {
  int id = blockIdx.x * 256 + threadIdx.x;  // 65536 threads
  if (id < 256) ksum[id] = 0.f;
  for (int t = id; t < 3 * 65536; t += 65536) {
    int mat = t >> 16;
    int e = t & 65535;
    int c = e >> 8, d = e & 255;
    const float* src = (mat == 0) ? Wq : (mat == 1) ? Wk : Wv;
    u16* dst = (mat == 0) ? WqF : (mat == 1) ? WkF : WvF;
    int idx = (((c >> 5) * 8 + (d >> 5)) * 2 + ((c >> 4) & 1)) * 512 +
              ((d >> 3) & 3) * 128 + (c & 15) * 8 + (d & 7);
    dst[idx] = (u16)bf16_1(src[e]);
  }
  if (S > 0) {  // shared slots need zeroed accumulators
    float4 z4 = {0.f, 0.f, 0.f, 0.f};
    float4* kz = (float4*)(kvp + (size_t)E * 65536);
    int total = S * 16384;
    for (int t = id; t < total; t += 65536) kz[t] = z4;
  }
}

// -------------------------------------------------------------- phase 1 -----
// 256 wgs x 1024 thr (16 waves), 1024 rows/wg in 16 tiles of 64 rows.
// Per tile: stage x->LDS (bf16, swizzled, lane-contiguous coalesced loads),
// fused k/v GEMMs (wave w owns cols 16w..16w+16; W frags streamed from L2),
// elu+1 on k, transpose k,v into LDS, kv += kT x vT into 64 accs/wave.
// End: ksum atomics + kv partial writeout (store if exclusive slot).
__global__ __launch_bounds__(1024, 4) void phase1_kernel(
    const float* __restrict__ x, const u16* __restrict__ WkF,
    const u16* __restrict__ WvF, float* __restrict__ kvp, float* __restrict__ ksum,
    int E, int S) {
  __shared__ __align__(16) u16 xv_l[16384];  // x (swizzled) then vT
  __shared__ __align__(16) u16 kT_l[16384];  // kT
  const int tid = threadIdx.x;
  const int lane = tid & 63;
  const int w = tid >> 6;    // wave 0..15
  const int m = lane & 15;   // MFMA m/n index
  const int q = lane >> 4;   // quad 0..3
  const int wg = blockIdx.x;

  const f32x4 fz = {0.f, 0.f, 0.f, 0.f};
  f32x4 kvacc[16];
#pragma unroll
  for (int tr = 0; tr < 16; ++tr) kvacc[tr] = fz;
  float ksl = 0.f;

  // fragment base for this wave's 16-col block: col-block w>>1, half w&1
  const int fb0 = (((w >> 1) * 8) * 2 + (w & 1)) * 512 + lane * 8;
  // staging geometry (constant per thread): float4 f = kk*1024+tid covers
  // row r = kk*16 + (tid>>6), cols 4*(tid&63)..+3
  const int sdb = (tid & 63) >> 1;
  const int ssw = sdb & 7;
  const int scw = 4 * (tid & 1);
  const int srb = tid >> 6;
  const int col = 16 * w + m;

  for (int it = 0; it < 16; ++it) {
    const int row0 = wg * 1024 + it * 64;
    __syncthreads();  // protect xv_l/kT_l vs previous iteration's kv reads
    {  // stage x tile [64][256] -> bf16, d-block-major with r-XOR swizzle
      const float4* xp = (const float4*)(x + (size_t)row0 * 256);
      float4 f0 = xp[tid];
      float4 f1 = xp[1024 + tid];
      float4 f2 = xp[2048 + tid];
      float4 f3 = xp[3072 + tid];
      uint2 u;
      u.x = bf16pk(f0.x, f0.y); u.y = bf16pk(f0.z, f0.w);
      *(uint2*)&xv_l[sdb * 512 + (((srb) ^ ssw) << 3) + scw] = u;
      u.x = bf16pk(f1.x, f1.y); u.y = bf16pk(f1.z, f1.w);
      *(uint2*)&xv_l[sdb * 512 + (((16 + srb) ^ ssw) << 3) + scw] = u;
      u.x = bf16pk(f2.x, f2.y); u.y = bf16pk(f2.z, f2.w);
      *(uint2*)&xv_l[sdb * 512 + (((32 + srb) ^ ssw) << 3) + scw] = u;
      u.x = bf16pk(f3.x, f3.y); u.y = bf16pk(f3.z, f3.w);
      *(uint2*)&xv_l[sdb * 512 + (((48 + srb) ^ ssw) << 3) + scw] = u;
    }
    __syncthreads();
    f32x4 kacc[4], vacc[4];
#pragma unroll
    for (int rt = 0; rt < 4; ++rt) { kacc[rt] = fz; vacc[rt] = fz; }
#pragma unroll
    for (int ks = 0; ks < 8; ++ks) {
      const int fb = fb0 + ks * 1024;
      short8 wk = *(const short8*)(WkF + fb);
      short8 wv = *(const short8*)(WvF + fb);
      const int db = 4 * ks + q;
      const int sw = db & 7;
      const u16* xb = &xv_l[db * 512];
#pragma unroll
      for (int rt = 0; rt < 4; ++rt) {
        short8 af = *(const short8*)&xb[((16 * rt + m) ^ sw) << 3];
        kacc[rt] = MFMA16(af, wk, kacc[rt]);
        vacc[rt] = MFMA16(af, wv, vacc[rt]);
      }
    }
    __syncthreads();  // all x reads done; xv_l reusable as vT
    // elu+1 on k, accumulate ksum, write kT and vT: element (col,row r) at
    // (r>>3)*2048 + col*8 + (r&7); C/D rows contiguous in groups of 4 -> b64
#pragma unroll
    for (int rt = 0; rt < 4; ++rt) {
      f32x4 kk = kacc[rt];
      float e0 = kk[0] > 0.f ? kk[0] + 1.f : __expf(kk[0]);
      float e1 = kk[1] > 0.f ? kk[1] + 1.f : __expf(kk[1]);
      float e2 = kk[2] > 0.f ? kk[2] + 1.f : __expf(kk[2]);
      float e3 = kk[3] > 0.f ? kk[3] + 1.f : __expf(kk[3]);
      ksl += (e0 + e1) + (e2 + e3);
      int pos = (2 * rt + (q >> 1)) * 2048 + col * 8 + 4 * (q & 1);
      uint2 kp;
      kp.x = bf16pk(e0, e1);
      kp.y = bf16pk(e2, e3);
      *(uint2*)&kT_l[pos] = kp;
      f32x4 vv = vacc[rt];
      uint2 vp;
      vp.x = bf16pk(vv[0], vv[1]);
      vp.y = bf16pk(vv[2], vv[3]);
      *(uint2*)&xv_l[pos] = vp;
    }
    __syncthreads();
    // kv accumulation: wave w owns kv[:, 16w..16w+16)
#pragma unroll
    for (int kc = 0; kc < 2; ++kc) {
      const int rbb = (4 * kc + q) * 2048;
      short8 bf = *(const short8*)&xv_l[rbb + col * 8];
#pragma unroll
      for (int tr = 0; tr < 16; ++tr) {
        short8 af = *(const short8*)&kT_l[rbb + (16 * tr + m) * 8];
        kvacc[tr] = MFMA16(af, bf, kvacc[tr]);
      }
    }
  }
  // ksum: reduce over quads (rows live in regs across q), one atomic per col
  float s = ksl;
  s += __shfl_xor(s, 16);
  s += __shfl_xor(s, 32);
  if (q == 0) atomicAdd(&ksum[col], s);
  // kv partial writeout: exclusive slots store, shared slots atomic
  const int slot = (wg < E) ? wg : (E + ((wg - E) & (S - 1)));
  float* dst = kvp + (size_t)slot * 65536;
  if (wg < E) {
#pragma unroll
    for (int tr = 0; tr < 16; ++tr)
#pragma unroll
      for (int e = 0; e < 4; ++e)
        dst[(16 * tr + 4 * q + e) * 256 + col] = kvacc[tr][e];
  } else {
#pragma unroll
    for (int tr = 0; tr < 16; ++tr)
#pragma unroll
      for (int e = 0; e < 4; ++e)
        atomicAdd(&dst[(16 * tr + 4 * q + e) * 256 + col], kvacc[tr][e]);
  }
}

// ---------------------------------------------------------------- mid -------
__global__ void mid1_kernel(const float* __restrict__ kvp, float* __restrict__ kv_red,
                            int nslots) {
  int id = blockIdx.x * 256 + threadIdx.x;  // 16384 threads, one float4 each
  float4 s = {0.f, 0.f, 0.f, 0.f};
  const float4* kp = (const float4*)kvp;
  for (int p = 0; p < nslots; ++p) {
    float4 v = kp[(size_t)p * 16384 + id];
    s.x += v.x; s.y += v.y; s.z += v.z; s.w += v.w;
  }
  ((float4*)kv_red)[id] = s;
}

// M[i][j] = sum_c kv[i][c] * Wo[j][c]; store as pre-swizzled bf16 B-fragment
__global__ void mid2_kernel(const float* __restrict__ kv_red,
                            const float* __restrict__ Wo, u16* __restrict__ MF) {
  __shared__ float kr[256];
  const int i = blockIdx.x;    // k-dim (q channel)
  const int j = threadIdx.x;   // out channel
  kr[j] = kv_red[i * 256 + j];
  __syncthreads();
  float acc = 0.f;
  const float* wo = Wo + (size_t)j * 256;
#pragma unroll 8
  for (int c = 0; c < 256; ++c) acc += kr[c] * wo[c];
  MF[(((j >> 5) * 8 + (i >> 5)) * 2 + ((j >> 4) & 1)) * 512 + ((i >> 3) & 3) * 128 +
     (j & 15) * 8 + (i & 7)] = (u16)bf16_1(acc);
}

// -------------------------------------------------------------- phase 2 -----
// q = elu(xWq^T)+1; s = q@ksum (fp32, shuffle+LDS-atomic); out = (q@M)*z + bo
// 256 wgs x 1024 thr; next-tile register prefetch hides staging latency.
__global__ __launch_bounds__(1024, 4) void phase2_kernel(
    const float* __restrict__ x, const u16* __restrict__ WqF,
    const u16* __restrict__ MF, const float* __restrict__ ksum,
    const float* __restrict__ bo, float* __restrict__ out) {
  __shared__ __align__(16) u16 xq_l[16384];  // x then q (same swizzle)
  __shared__ float s_l[64];
  const int tid = threadIdx.x;
  const int lane = tid & 63;
  const int w = tid >> 6;
  const int m = lane & 15;
  const int q = lane >> 4;
  const int wg = blockIdx.x;
  const f32x4 fz = {0.f, 0.f, 0.f, 0.f};

  const int fb0 = (((w >> 1) * 8) * 2 + (w & 1)) * 512 + lane * 8;
  short8 mf[8];  // persistent M fragments (32 VGPRs)
#pragma unroll
  for (int ks = 0; ks < 8; ++ks) mf[ks] = *(const short8*)(MF + fb0 + ks * 1024);
  const float ks0 = ksum[16 * w + m];
  const float b0 = bo[16 * w + m];

  const int sdb = (tid & 63) >> 1;
  const int ssw = sdb & 7;
  const int scw = 4 * (tid & 1);
  const int srb = tid >> 6;
  const int cq = 16 * w + m;

  // prologue prefetch (tile 0)
  float4 pf0, pf1, pf2, pf3;
  {
    const float4* xp = (const float4*)(x + (size_t)wg * 1024 * 256);
    pf0 = xp[tid]; pf1 = xp[1024 + tid]; pf2 = xp[2048 + tid]; pf3 = xp[3072 + tid];
  }

  for (int it = 0; it < 16; ++it) {
    const int row0 = wg * 1024 + it * 64;
    __syncthreads();  // prev qM reads of xq_l + s_l reads done
    {  // write prefetched x tile -> bf16 swizzled LDS
      uint2 u;
      u.x = bf16pk(pf0.x, pf0.y); u.y = bf16pk(pf0.z, pf0.w);
      *(uint2*)&xq_l[sdb * 512 + (((srb) ^ ssw) << 3) + scw] = u;
      u.x = bf16pk(pf1.x, pf1.y); u.y = bf16pk(pf1.z, pf1.w);
      *(uint2*)&xq_l[sdb * 512 + (((16 + srb) ^ ssw) << 3) + scw] = u;
      u.x = bf16pk(pf2.x, pf2.y); u.y = bf16pk(pf2.z, pf2.w);
      *(uint2*)&xq_l[sdb * 512 + (((32 + srb) ^ ssw) << 3) + scw] = u;
      u.x = bf16pk(pf3.x, pf3.y); u.y = bf16pk(pf3.z, pf3.w);
      *(uint2*)&xq_l[sdb * 512 + (((48 + srb) ^ ssw) << 3) + scw] = u;
      if (tid < 64) s_l[tid] = 0.f;
    }
    __syncthreads();
    if (it < 15) {  // issue next tile's loads; they complete under the GEMMs
      const float4* xp = (const float4*)(x + (size_t)(row0 + 64) * 256);
      pf0 = xp[tid]; pf1 = xp[1024 + tid]; pf2 = xp[2048 + tid]; pf3 = xp[3072 + tid];
    }
    f32x4 qacc[4];
#pragma unroll
    for (int rt = 0; rt < 4; ++rt) qacc[rt] = fz;
#pragma unroll
    for (int ks = 0; ks < 8; ++ks) {
      short8 wq = *(const short8*)(WqF + fb0 + ks * 1024);
      const int db = 4 * ks + q;
      const int sw = db & 7;
      const u16* xb = &xq_l[db * 512];
#pragma unroll
      for (int rt = 0; rt < 4; ++rt) {
        short8 af = *(const short8*)&xb[((16 * rt + m) ^ sw) << 3];
        qacc[rt] = MFMA16(af, wq, qacc[rt]);
      }
    }
    // elu+1 and s partials (fp32, pre-quantization)
#pragma unroll
    for (int rt = 0; rt < 4; ++rt) {
      f32x4 a = qacc[rt];
      a[0] = a[0] > 0.f ? a[0] + 1.f : __expf(a[0]);
      a[1] = a[1] > 0.f ? a[1] + 1.f : __expf(a[1]);
      a[2] = a[2] > 0.f ? a[2] + 1.f : __expf(a[2]);
      a[3] = a[3] > 0.f ? a[3] + 1.f : __expf(a[3]);
      qacc[rt] = a;
#pragma unroll
      for (int e = 0; e < 4; ++e) {
        float val = a[e] * ks0;
        val += __shfl_xor(val, 1);
        val += __shfl_xor(val, 2);
        val += __shfl_xor(val, 4);
        val += __shfl_xor(val, 8);
        if (m == 0) atomicAdd(&s_l[16 * rt + 4 * q + e], val);
      }
    }
    __syncthreads();  // x reads + s atomics done; reuse xq_l for q
    {
      const int dbq = cq >> 3, swq = dbq & 7, cwq = cq & 7;
#pragma unroll
      for (int rt = 0; rt < 4; ++rt)
#pragma unroll
        for (int e = 0; e < 4; ++e) {
          int r = 16 * rt + 4 * q + e;
          xq_l[dbq * 512 + ((r ^ swq) << 3) + cwq] = (u16)bf16_1(qacc[rt][e]);
        }
    }
    __syncthreads();
    f32x4 tacc[4];
#pragma unroll
    for (int rt = 0; rt < 4; ++rt) tacc[rt] = fz;
#pragma unroll
    for (int ks = 0; ks < 8; ++ks) {
      const int db = 4 * ks + q;
      const int sw = db & 7;
      const u16* xb = &xq_l[db * 512];
#pragma unroll
      for (int rt = 0; rt < 4; ++rt) {
        short8 af = *(const short8*)&xb[((16 * rt + m) ^ sw) << 3];
        tacc[rt] = MFMA16(af, mf[ks], tacc[rt]);
      }
    }
#pragma unroll
    for (int rt = 0; rt < 4; ++rt)
#pragma unroll
      for (int e = 0; e < 4; ++e) {
        int r = 16 * rt + 4 * q + e;
        float z = __builtin_amdgcn_rcpf(fmaxf(s_l[r], 1e-6f));
        out[(size_t)(row0 + r) * 256 + cq] = tacc[rt][e] * z + b0;
      }
  }
}

// ---------------------------------------------------------------- host ------
extern "C" void kernel_launch(void* const* d_in, const int* in_sizes, int n_in,
                              void* d_out, int out_size, void* d_ws, size_t ws_size,
                              hipStream_t stream) {
  const float* x = (const float*)d_in[0];
  const float* Wq = (const float*)d_in[1];
  const float* Wk = (const float*)d_in[2];
  const float* Wv = (const float*)d_in[3];
  const float* Wo = (const float*)d_in[4];
  const float* bo = (const float*)d_in[5];
  float* out = (float*)d_out;

  // ws layout: kvp[nslots*65536 f] | ksum[256 f] | kv_red[65536 f] | MF,WqF,WkF,WvF
  const size_t fixedB = 1024 + 262144 + 4 * 131072;  // 787456
  long long avail = (long long)ws_size - (long long)fixedB;
  int slots = avail > 0 ? (int)(avail / 262144) : 1;
  if (slots < 1) slots = 1;
  if (slots > 256) slots = 256;
  int E, S;
  if (slots >= 256) { E = 256; S = 0; }        // all 256 wgs exclusive
  else if (slots >= 8) { E = slots - 4; S = 4; }  // few overflow wgs share 4 slots
  else if (slots >= 2) { E = slots - 1; S = 1; }
  else { E = 0; S = 1; }
  const int nslots = E + S;

  char* base = (char*)d_ws;
  float* kvp = (float*)base;
  float* ksum = (float*)(base + (size_t)nslots * 262144);
  float* kvred = ksum + 256;
  u16* MF = (u16*)(kvred + 65536);
  u16* WqF = MF + 65536;
  u16* WkF = WqF + 65536;
  u16* WvF = WkF + 65536;

  prep_kernel<<<256, 256, 0, stream>>>(Wq, Wk, Wv, WqF, WkF, WvF, kvp, ksum, E, S);
  phase1_kernel<<<256, 1024, 0, stream>>>(x, WkF, WvF, kvp, ksum, E, S);
  mid1_kernel<<<64, 256, 0, stream>>>(kvp, kvred, nslots);
  mid2_kernel<<<256, 256, 0, stream>>>(kvred, Wo, MF);
  phase2_kernel<<<256, 1024, 0, stream>>>(x, WqF, MF, ksum, bo, out);
}

// Round 3
// 1016.198 us; speedup vs baseline: 1.0302x; 1.0302x over previous
//
#include <hip/hip_runtime.h>
#include <cstdint>

// LinearGlobalAttention: out = ((elu(xWq^T)+1) @ M) * z + bo
//   M = (k^T v) @ Wo^T,  k = elu(xWk^T)+1, v = xWv^T, z = 1/max(q@ksum,1e-6)
// N=262144, C=256. Two fused passes over x + tiny mid kernels.
// MFMA 16x16x32 bf16; verified layouts: A[m=lane&15][k=(lane>>4)*8+j],
// B[k=(lane>>4)*8+j][n=lane&15], C/D: col(N)=lane&15, row(M)=(lane>>4)*4+reg.
//
// R2: 2-barrier/tile schedule with double-buffered x in LDS (async regions
// replace the 4-barrier lockstep that left >50% idle); phase2 second GEMM
// computes out^T via mfma(M^T-frag, q-frag) -> float4 nontemporal stores
// (kills partial-line RFO overfetch); mid1 folded into mid2.
// R3: fix nontemporal store type (ext_vector f32x4, not HIP float4).

typedef __attribute__((ext_vector_type(8))) short short8;
typedef __attribute__((ext_vector_type(4))) float f32x4;
typedef unsigned short u16;
typedef unsigned int u32;

#define MFMA16(a, b, c) __builtin_amdgcn_mfma_f32_16x16x32_bf16(a, b, c, 0, 0, 0)

__device__ __forceinline__ u32 bf16_1(float f) {
  u32 u = __float_as_uint(f);
  return (u + 0x7FFFu + ((u >> 16) & 1u)) >> 16;  // RNE
}
__device__ __forceinline__ u32 bf16pk(float lo, float hi) {
  return bf16_1(lo) | (bf16_1(hi) << 16);
}

// ---------------------------------------------------------------- prep ------
// Zero ksum + the S shared kv-partial slots; build pre-swizzled bf16 B-operand
// fragments for Wq/Wk/Wv: element (c,d) of W (y = x W^T, so B[k=d][n=c]=W[c][d]).
__global__ void prep_kernel(const float* __restrict__ Wq, const float* __restrict__ Wk,
                            const float* __restrict__ Wv, u16* __restrict__ WqF,
                            u16* __restrict__ WkF, u16* __restrict__ WvF,
                            float* __restrict__ kvp, float* __restrict__ ksum,
                            int E, int S) {
  int id = blockIdx.x * 256 + threadIdx.x;  // 65536 threads
  if (id < 256) ksum[id] = 0.f;
  for (int t = id; t < 3 * 65536; t += 65536) {
    int mat = t >> 16;
    int e = t & 65535;
    int c = e >> 8, d = e & 255;
    const float* src = (mat == 0) ? Wq : (mat == 1) ? Wk : Wv;
    u16* dst = (mat == 0) ? WqF : (mat == 1) ? WkF : WvF;
    int idx = (((c >> 5) * 8 + (d >> 5)) * 2 + ((c >> 4) & 1)) * 512 +
              ((d >> 3) & 3) * 128 + (c & 15) * 8 + (d & 7);
    dst[idx] = (u16)bf16_1(src[e]);
  }
  if (S > 0) {  // shared slots need zeroed accumulators
    float4 z4 = {0.f, 0.f, 0.f, 0.f};
    float4* kz = (float4*)(kvp + (size_t)E * 65536);
    int total = S * 16384;
    for (int t = id; t < total; t += 65536) kz[t] = z4;
  }
}

// -------------------------------------------------------------- phase 1 -----
// 256 wgs x 1024 thr (16 waves), 1024 rows/wg in 16 tiles of 64 rows.
// 2 barriers/tile: region A = {k/v GEMM from xb[p], elu+pack, kT/vT write};
// region B = {stage tile t+1 -> xb[p^1], kv MFMA from kT/vT}.
__global__ __launch_bounds__(1024, 4) void phase1_kernel(
    const float* __restrict__ x, const u16* __restrict__ WkF,
    const u16* __restrict__ WvF, float* __restrict__ kvp, float* __restrict__ ksum,
    int E, int S) {
  __shared__ __align__(16) u16 xb_l[2][16384];  // x tiles, double-buffered
  __shared__ __align__(16) u16 kT_l[16384];     // kT
  __shared__ __align__(16) u16 vT_l[16384];     // vT
  const int tid = threadIdx.x;
  const int lane = tid & 63;
  const int w = tid >> 6;    // wave 0..15
  const int m = lane & 15;   // MFMA m/n index
  const int q = lane >> 4;   // quad 0..3
  const int wg = blockIdx.x;

  const f32x4 fz = {0.f, 0.f, 0.f, 0.f};
  f32x4 kvacc[16];
#pragma unroll
  for (int tr = 0; tr < 16; ++tr) kvacc[tr] = fz;
  float ksl = 0.f;

  const int fb0 = (((w >> 1) * 8) * 2 + (w & 1)) * 512 + lane * 8;
  const int sdb = (tid & 63) >> 1;
  const int ssw = sdb & 7;
  const int spos0 = sdb * 512 + 4 * (tid & 1);
  const int srb = tid >> 6;
  const int col = 16 * w + m;

  // stage a 64-row tile (f32 -> bf16, d-block-major, r-XOR swizzle), 4 loads
  auto stage = [&](u16* dst, const float4* xp) {
    float4 f0 = xp[tid], f1 = xp[1024 + tid];
    uint2 u;
    u.x = bf16pk(f0.x, f0.y); u.y = bf16pk(f0.z, f0.w);
    *(uint2*)&dst[spos0 + ((srb ^ ssw) << 3)] = u;
    u.x = bf16pk(f1.x, f1.y); u.y = bf16pk(f1.z, f1.w);
    *(uint2*)&dst[spos0 + (((16 + srb) ^ ssw) << 3)] = u;
    float4 f2 = xp[2048 + tid], f3 = xp[3072 + tid];
    u.x = bf16pk(f2.x, f2.y); u.y = bf16pk(f2.z, f2.w);
    *(uint2*)&dst[spos0 + (((32 + srb) ^ ssw) << 3)] = u;
    u.x = bf16pk(f3.x, f3.y); u.y = bf16pk(f3.z, f3.w);
    *(uint2*)&dst[spos0 + (((48 + srb) ^ ssw) << 3)] = u;
  };

  stage(xb_l[0], (const float4*)(x + (size_t)wg * 1024 * 256));
  __syncthreads();

  for (int it = 0; it < 16; ++it) {
    const u16* xcur = xb_l[it & 1];
    f32x4 kacc[4], vacc[4];
#pragma unroll
    for (int rt = 0; rt < 4; ++rt) { kacc[rt] = fz; vacc[rt] = fz; }
#pragma unroll
    for (int ks = 0; ks < 8; ++ks) {
      const int fb = fb0 + ks * 1024;
      short8 wk = *(const short8*)(WkF + fb);
      short8 wv = *(const short8*)(WvF + fb);
      const int db = 4 * ks + q;
      const int sw = db & 7;
      const u16* xbp = &xcur[db * 512];
#pragma unroll
      for (int rt = 0; rt < 4; ++rt) {
        short8 af = *(const short8*)&xbp[((16 * rt + m) ^ sw) << 3];
        kacc[rt] = MFMA16(af, wk, kacc[rt]);
        vacc[rt] = MFMA16(af, wv, vacc[rt]);
      }
    }
    // elu+1 on k, ksum partial, write kT and vT: element (col, row r) at
    // (r>>3)*2048 + col*8 + (r&7)
#pragma unroll
    for (int rt = 0; rt < 4; ++rt) {
      f32x4 kk = kacc[rt];
      float e0 = kk[0] > 0.f ? kk[0] + 1.f : __expf(kk[0]);
      float e1 = kk[1] > 0.f ? kk[1] + 1.f : __expf(kk[1]);
      float e2 = kk[2] > 0.f ? kk[2] + 1.f : __expf(kk[2]);
      float e3 = kk[3] > 0.f ? kk[3] + 1.f : __expf(kk[3]);
      ksl += (e0 + e1) + (e2 + e3);
      int pos = (2 * rt + (q >> 1)) * 2048 + col * 8 + 4 * (q & 1);
      uint2 kp;
      kp.x = bf16pk(e0, e1);
      kp.y = bf16pk(e2, e3);
      *(uint2*)&kT_l[pos] = kp;
      f32x4 vv = vacc[rt];
      uint2 vp;
      vp.x = bf16pk(vv[0], vv[1]);
      vp.y = bf16pk(vv[2], vv[3]);
      *(uint2*)&vT_l[pos] = vp;
    }
    __syncthreads();  // A: kT/vT ready; xb[it&1] free
    if (it < 15)
      stage(xb_l[(it + 1) & 1],
            (const float4*)(x + (size_t)(wg * 1024 + (it + 1) * 64) * 256));
    // kv accumulation: wave w owns kv[:, 16w..16w+16)
#pragma unroll
    for (int kc = 0; kc < 2; ++kc) {
      const int rbb = (4 * kc + q) * 2048;
      short8 bf = *(const short8*)&vT_l[rbb + col * 8];
#pragma unroll
      for (int tr = 0; tr < 16; ++tr) {
        short8 af = *(const short8*)&kT_l[rbb + (16 * tr + m) * 8];
        kvacc[tr] = MFMA16(af, bf, kvacc[tr]);
      }
    }
    __syncthreads();  // B: kv reads done; xb[(it+1)&1] staged
  }
  // ksum: reduce over quads, one atomic per col
  float s = ksl;
  s += __shfl_xor(s, 16);
  s += __shfl_xor(s, 32);
  if (q == 0) atomicAdd(&ksum[col], s);
  // kv partial writeout: exclusive slots store, shared slots atomic
  const int slot = (wg < E) ? wg : (E + ((wg - E) & (S - 1)));
  float* dst = kvp + (size_t)slot * 65536;
  if (wg < E) {
#pragma unroll
    for (int tr = 0; tr < 16; ++tr)
#pragma unroll
      for (int e = 0; e < 4; ++e)
        dst[(16 * tr + 4 * q + e) * 256 + col] = kvacc[tr][e];
  } else {
#pragma unroll
    for (int tr = 0; tr < 16; ++tr)
#pragma unroll
      for (int e = 0; e < 4; ++e)
        atomicAdd(&dst[(16 * tr + 4 * q + e) * 256 + col], kvacc[tr][e]);
  }
}

// ---------------------------------------------------------------- mid -------
// Fused reduce + M build. Block i: kv[i][:] = sum_p kvp[p][i][:], then
// M[i][j] = sum_c kv[i][c]*Wo[j][c], stored as pre-swizzled bf16 A-fragment
// of M^T: A[m'=outch j][k=qch i] at MFt[((j>>4)*8+(i>>5))*512 +
// (((i>>3)&3)*16+(j&15))*8 + (i&7)].
__global__ void mid2_kernel(const float* __restrict__ kvp,
                            const float* __restrict__ Wo, u16* __restrict__ MFt,
                            int nslots) {
  __shared__ float kr[256];
  const int i = blockIdx.x;    // k-dim (q channel)
  const int j = threadIdx.x;   // out channel
  float s = 0.f;
  const float* src = kvp + i * 256 + j;
#pragma unroll 4
  for (int p = 0; p < nslots; ++p) s += src[(size_t)p * 65536];
  kr[j] = s;
  __syncthreads();
  float acc = 0.f;
  const float* wo = Wo + (size_t)j * 256;
#pragma unroll 8
  for (int c = 0; c < 256; ++c) acc += kr[c] * wo[c];
  MFt[((j >> 4) * 8 + (i >> 5)) * 512 + (((i >> 3) & 3) * 16 + (j & 15)) * 8 +
      (i & 7)] = (u16)bf16_1(acc);
}

// -------------------------------------------------------------- phase 2 -----
// q = elu(xWq^T)+1; s = q@ksum (fp32, shuffle+LDS-atomic); out = (q@M)*z + bo.
// 2 barriers/tile; second GEMM computes out^T tiles: mfma(A=M^T frag,
// B=q frag) -> lane holds 4 consecutive out-channels -> float4 nt stores.
__global__ __launch_bounds__(1024, 4) void phase2_kernel(
    const float* __restrict__ x, const u16* __restrict__ WqF,
    const u16* __restrict__ MFt, const float* __restrict__ ksum,
    const float* __restrict__ bo, float* __restrict__ out) {
  __shared__ __align__(16) u16 xb_l[2][16384];  // x tiles, double-buffered
  __shared__ __align__(16) u16 qb_l[16384];     // q tile (same swizzle)
  __shared__ float s_l[2][64];
  const int tid = threadIdx.x;
  const int lane = tid & 63;
  const int w = tid >> 6;
  const int m = lane & 15;
  const int q = lane >> 4;
  const int wg = blockIdx.x;
  const f32x4 fz = {0.f, 0.f, 0.f, 0.f};

  const int fb0 = (((w >> 1) * 8) * 2 + (w & 1)) * 512 + lane * 8;  // WqF B-frags
  short8 mft[8];  // persistent M^T A-fragments (32 VGPRs); wave w: outch 16w..
#pragma unroll
  for (int ks = 0; ks < 8; ++ks)
    mft[ks] = *(const short8*)(MFt + (w * 8 + ks) * 512 + lane * 8);
  const float ks0 = ksum[16 * w + m];
  const float4 bvec = *(const float4*)(bo + 16 * w + 4 * q);

  const int sdb = (tid & 63) >> 1;
  const int ssw = sdb & 7;
  const int spos0 = sdb * 512 + 4 * (tid & 1);
  const int srb = tid >> 6;
  const int dbq = (16 * w + m) >> 3;  // q-write geometry (col = 16w+m)
  const int swq = dbq & 7;
  const int cwq = m & 7;

  auto stage = [&](u16* dst, const float4* xp) {
    float4 f0 = xp[tid], f1 = xp[1024 + tid];
    uint2 u;
    u.x = bf16pk(f0.x, f0.y); u.y = bf16pk(f0.z, f0.w);
    *(uint2*)&dst[spos0 + ((srb ^ ssw) << 3)] = u;
    u.x = bf16pk(f1.x, f1.y); u.y = bf16pk(f1.z, f1.w);
    *(uint2*)&dst[spos0 + (((16 + srb) ^ ssw) << 3)] = u;
    float4 f2 = xp[2048 + tid], f3 = xp[3072 + tid];
    u.x = bf16pk(f2.x, f2.y); u.y = bf16pk(f2.z, f2.w);
    *(uint2*)&dst[spos0 + (((32 + srb) ^ ssw) << 3)] = u;
    u.x = bf16pk(f3.x, f3.y); u.y = bf16pk(f3.z, f3.w);
    *(uint2*)&dst[spos0 + (((48 + srb) ^ ssw) << 3)] = u;
  };

  stage(xb_l[0], (const float4*)(x + (size_t)wg * 1024 * 256));
  if (tid < 64) s_l[0][tid] = 0.f;
  __syncthreads();

  for (int it = 0; it < 16; ++it) {
    const u16* xcur = xb_l[it & 1];
    const int sp = it & 1;
    const int row0 = wg * 1024 + it * 64;
    f32x4 qacc[4];
#pragma unroll
    for (int rt = 0; rt < 4; ++rt) qacc[rt] = fz;
#pragma unroll
    for (int ks = 0; ks < 8; ++ks) {
      short8 wq = *(const short8*)(WqF + fb0 + ks * 1024);
      const int db = 4 * ks + q;
      const int sw = db & 7;
      const u16* xbp = &xcur[db * 512];
#pragma unroll
      for (int rt = 0; rt < 4; ++rt) {
        short8 af = *(const short8*)&xbp[((16 * rt + m) ^ sw) << 3];
        qacc[rt] = MFMA16(af, wq, qacc[rt]);
      }
    }
    // elu+1, s partials (fp32), write q -> LDS (bf16, same swizzle as x)
#pragma unroll
    for (int rt = 0; rt < 4; ++rt) {
      f32x4 a = qacc[rt];
      a[0] = a[0] > 0.f ? a[0] + 1.f : __expf(a[0]);
      a[1] = a[1] > 0.f ? a[1] + 1.f : __expf(a[1]);
      a[2] = a[2] > 0.f ? a[2] + 1.f : __expf(a[2]);
      a[3] = a[3] > 0.f ? a[3] + 1.f : __expf(a[3]);
#pragma unroll
      for (int e = 0; e < 4; ++e) {
        float val = a[e] * ks0;
        val += __shfl_xor(val, 1);
        val += __shfl_xor(val, 2);
        val += __shfl_xor(val, 4);
        val += __shfl_xor(val, 8);
        if (m == 0) atomicAdd(&s_l[sp][16 * rt + 4 * q + e], val);
      }
#pragma unroll
      for (int e = 0; e < 4; ++e) {
        int r = 16 * rt + 4 * q + e;
        qb_l[dbq * 512 + ((r ^ swq) << 3) + cwq] = (u16)bf16_1(a[e]);
      }
    }
    __syncthreads();  // A: q + s_l[sp] ready; xb[it&1] free
    if (it < 15)
      stage(xb_l[(it + 1) & 1],
            (const float4*)(x + (size_t)(row0 + 64) * 256));
    if (tid < 64) s_l[sp ^ 1][tid] = 0.f;
    // out^T GEMM: tacc = sum_ks mfma(M^T frag, q frag)
    f32x4 tacc[4];
#pragma unroll
    for (int rt = 0; rt < 4; ++rt) tacc[rt] = fz;
#pragma unroll
    for (int ks = 0; ks < 8; ++ks) {
      const int db = 4 * ks + q;
      const int sw = db & 7;
      const u16* xq = &qb_l[db * 512];
#pragma unroll
      for (int rt = 0; rt < 4; ++rt) {
        short8 af = *(const short8*)&xq[((16 * rt + m) ^ sw) << 3];
        tacc[rt] = MFMA16(mft[ks], af, tacc[rt]);
      }
    }
    // stores: lane (q,m) holds out[row0+16rt+m][16w+4q+e], e=0..3
#pragma unroll
    for (int rt = 0; rt < 4; ++rt) {
      float zz = __builtin_amdgcn_rcpf(fmaxf(s_l[sp][16 * rt + m], 1e-6f));
      f32x4 o;
      o[0] = tacc[rt][0] * zz + bvec.x;
      o[1] = tacc[rt][1] * zz + bvec.y;
      o[2] = tacc[rt][2] * zz + bvec.z;
      o[3] = tacc[rt][3] * zz + bvec.w;
      f32x4* op = (f32x4*)(out + (size_t)(row0 + 16 * rt + m) * 256 + 16 * w + 4 * q);
      __builtin_nontemporal_store(o, op);
    }
    __syncthreads();  // B: q reads done; xb[(it+1)&1] staged
  }
}

// ---------------------------------------------------------------- host ------
extern "C" void kernel_launch(void* const* d_in, const int* in_sizes, int n_in,
                              void* d_out, int out_size, void* d_ws, size_t ws_size,
                              hipStream_t stream) {
  const float* x = (const float*)d_in[0];
  const float* Wq = (const float*)d_in[1];
  const float* Wk = (const float*)d_in[2];
  const float* Wv = (const float*)d_in[3];
  const float* Wo = (const float*)d_in[4];
  const float* bo = (const float*)d_in[5];
  float* out = (float*)d_out;

  // ws layout: kvp[nslots*65536 f] | ksum[256 f] | MFt,WqF,WkF,WvF (u16)
  const size_t fixedB = 1024 + 4 * 131072;  // 525312
  long long avail = (long long)ws_size - (long long)fixedB;
  int slots = avail > 0 ? (int)(avail / 262144) : 1;
  if (slots < 1) slots = 1;
  if (slots > 256) slots = 256;
  int E, S;
  if (slots >= 256) { E = 256; S = 0; }           // all 256 wgs exclusive
  else if (slots >= 8) { E = slots - 4; S = 4; }  // few overflow wgs share 4 slots
  else if (slots >= 2) { E = slots - 1; S = 1; }
  else { E = 0; S = 1; }
  const int nslots = E + S;

  char* base = (char*)d_ws;
  float* kvp = (float*)base;
  float* ksum = (float*)(base + (size_t)nslots * 262144);
  u16* MFt = (u16*)(ksum + 256);
  u16* WqF = MFt + 65536;
  u16* WkF = WqF + 65536;
  u16* WvF = WkF + 65536;

  prep_kernel<<<256, 256, 0, stream>>>(Wq, Wk, Wv, WqF, WkF, WvF, kvp, ksum, E, S);
  phase1_kernel<<<256, 1024, 0, stream>>>(x, WkF, WvF, kvp, ksum, E, S);
  mid2_kernel<<<256, 256, 0, stream>>>(kvp, Wo, MFt, nslots);
  phase2_kernel<<<256, 1024, 0, stream>>>(x, WqF, MFt, ksum, bo, out);
}